// Round 10
// baseline (236.650 us; speedup 1.0000x reference)
//
#include <hip/hip_runtime.h>
#include <math.h>

typedef unsigned short u16;
typedef __attribute__((ext_vector_type(8))) short short8;   // 8 bf16 = 4 VGPRs
typedef __attribute__((ext_vector_type(4))) short short4v;  // 4 bf16 = 2 VGPRs
typedef __attribute__((ext_vector_type(4))) float f32x4;    // MFMA C/D frag
typedef __attribute__((ext_vector_type(4))) unsigned int uint4v;

constexpr int Bn = 4, Sn = 2048, Dn = 1024, Hn = 16;
constexpr float SCL = 0.125f * 1.44269504f;  // 1/sqrt(64) * log2(e), folded into Wq

__device__ __forceinline__ u16 f2bf(float f) {  // RNE float->bf16
  unsigned u = __float_as_uint(f);
  u += 0x7fffu + ((u >> 16) & 1u);
  return (u16)(u >> 16);
}

__device__ __forceinline__ f32x4 mfma32(short8 a, short8 b, f32x4 c) {
  return __builtin_amdgcn_mfma_f32_16x16x32_bf16(a, b, c, 0, 0, 0);
}

__device__ __forceinline__ void gl_lds16(const u16* g, u16* l) {
  __builtin_amdgcn_global_load_lds(
      (const __attribute__((address_space(1))) unsigned int*)g,
      (__attribute__((address_space(3))) unsigned int*)l, 16, 0, 0);
}

// Barrier brackets for the 8-phase schedule (R7-verified): sched_barrier(0)
// on both sides of every s_barrier pins program order (rule #18 family).
#define BAR_IN()                                          \
  do {                                                    \
    __builtin_amdgcn_sched_barrier(0);                    \
    __builtin_amdgcn_s_barrier();                         \
    asm volatile("s_waitcnt lgkmcnt(0)" ::: "memory");    \
    __builtin_amdgcn_sched_barrier(0);                    \
    __builtin_amdgcn_s_setprio(1);                        \
  } while (0)
#define BAR_OUT()                                         \
  do {                                                    \
    __builtin_amdgcn_s_setprio(0);                        \
    __builtin_amdgcn_sched_barrier(0);                    \
    __builtin_amdgcn_s_barrier();                         \
    __builtin_amdgcn_sched_barrier(0);                    \
  } while (0)
#define BAR_OUT_VM(N)                                     \
  do {                                                    \
    __builtin_amdgcn_s_setprio(0);                        \
    __builtin_amdgcn_sched_barrier(0);                    \
    asm volatile("s_waitcnt vmcnt(" #N ")" ::: "memory"); \
    __builtin_amdgcn_s_barrier();                         \
    __builtin_amdgcn_sched_barrier(0);                    \
  } while (0)

// ---------------------------------------------------------------------------
// One launch for all f32->bf16 casts. Blocks 0..8191: x. Then 1024 each for
// wq (pre-scaled by SCL), wk, wv, wo.
// ---------------------------------------------------------------------------
__global__ __launch_bounds__(256) void cast_all(
    const float4* __restrict__ x, const float4* __restrict__ wq,
    const float4* __restrict__ wk, const float4* __restrict__ wv,
    const float4* __restrict__ wo, ushort4* __restrict__ xb,
    ushort4* __restrict__ wqb, ushort4* __restrict__ wkb,
    ushort4* __restrict__ wvb, ushort4* __restrict__ wob) {
  const int blk = blockIdx.x;
  const float4* in;
  ushort4* out;
  int base;
  float s = 1.0f;
  if (blk < 8192) {
    in = x; out = xb; base = blk;
  } else if (blk < 9216) {
    in = wq; out = wqb; base = blk - 8192; s = SCL;
  } else if (blk < 10240) {
    in = wk; out = wkb; base = blk - 9216;
  } else if (blk < 11264) {
    in = wv; out = wvb; base = blk - 10240;
  } else {
    in = wo; out = wob; base = blk - 11264;
  }
  const int i = base * 256 + threadIdx.x;
  const float4 f = in[i];
  ushort4 o;
  o.x = f2bf(f.x * s); o.y = f2bf(f.y * s);
  o.z = f2bf(f.z * s); o.w = f2bf(f.w * s);
  out[i] = o;
}

// ---------------------------------------------------------------------------
// QKV GEMM, 256x256 tile, BK=32, 8 waves (512 thr), 8-phase counted-vmcnt
// schedule. R7's BK=64 port proved the schedule's steady-state (~990 TF,
// VALUBusy 14%) but died on grid quantization: 128 KB LDS -> 1 block/CU ->
// 384 blocks = 2 dispatch rounds. This version: BK=32 -> 64 KB LDS ->
// 2 blocks/CU -> all 384 blocks resident in ONE round, and co-resident
// blocks fill each other's barrier stalls.
// LDS u16[32768]: A bufs @0/8192 (256x32 each), B bufs @16384/24576.
// Stage unit = one full A or B K-tile (16 KB, 2 gl_lds16/thread). Chunk
// swizzle cg = cl^(row&3); reads spread uniformly 8 lanes per 4-bank slot
// = the b128 8-cycle floor (conflict-free in the m136 sense).
// Per iteration (2 K-tiles kc=2i, kc+1): 8 phases, quadrants
// (A0B0)(A0B1)(A1B1)(A1B0) per K-tile, 8 mfma each. Stage stream:
// ph1: B(kc+1), ph4: A(kc+2), ph5: B(kc+2), ph8: A(kc+3).
// vmcnt(2) at ph4 (completes A(kc+1),B(kc+1) for ph5-7; leaves A(kc+2)
// in flight) and ph8 (completes A(kc+2),B(kc+2) for next ph1-3; leaves
// A(kc+3)). Every stage write issues >=1 barrier after the last ds_read
// of the data it overwrites (lockstep phases bound wave skew). Tail
// (i=15): only ph1's B(31); vmcnt(0) at ph4. Prologue: A(0),B(0),A(1) +
// vmcnt(2).
// ---------------------------------------------------------------------------
__global__ __launch_bounds__(512, 2) void gemm_qkv8(
    const u16* __restrict__ A, const u16* __restrict__ Wq,
    const u16* __restrict__ Wk, const u16* __restrict__ Wv,
    u16* __restrict__ Cq, u16* __restrict__ Ck, u16* __restrict__ Vt) {
  __shared__ u16 lds[32768];  // 64 KB

  const int t = threadIdx.x;
  const int w8 = t >> 6, l = t & 63;
  const int wr = w8 >> 2, wc = w8 & 3;      // wave grid 2M x 4N
  const int q = l >> 4, r = l & 15;
  const int m0 = blockIdx.x * 256, n0 = blockIdx.y * 256;
  const int z = blockIdx.z;
  const u16* __restrict__ W = z == 0 ? Wq : z == 1 ? Wk : Wv;

  // Stage sources: chunk c = t + ii*512 (0..1023), row = c>>2 (0..255),
  // cl = c&3, swizzled global chunk cg = cl^(row&3); LDS dest linear c*8.
  const u16* asrc[2];
  const u16* wsrc[2];
#pragma unroll
  for (int ii = 0; ii < 2; ++ii) {
    const int c = t + ii * 512, row = c >> 2, cl = c & 3;
    const int cg = cl ^ (row & 3);
    asrc[ii] = A + (size_t)(m0 + row) * 1024 + cg * 8;
    wsrc[ii] = W + (size_t)(n0 + row) * 1024 + cg * 8;
  }

  auto STA = [&](int kt) {
#pragma unroll
    for (int ii = 0; ii < 2; ++ii)
      gl_lds16(asrc[ii] + kt * 32, &lds[(kt & 1) * 8192 + t * 8 + ii * 4096]);
  };
  auto STB = [&](int kt) {
#pragma unroll
    for (int ii = 0; ii < 2; ++ii)
      gl_lds16(wsrc[ii] + kt * 32,
               &lds[16384 + (kt & 1) * 8192 + t * 8 + ii * 4096]);
  };

  f32x4 acc[8][4] = {};
  short8 Af[4];      // current A quadrant (4 m2), K=32 -> 1 frag each
  short8 Bf[2][2];   // both B groups persist across phases

  const int rq = (q ^ (r & 3)) * 8;
  auto LDA = [&](int abase, int ag) {
#pragma unroll
    for (int m2 = 0; m2 < 4; ++m2)
      Af[m2] = *(const short8*)
          &lds[abase + (wr * 128 + ag * 64 + m2 * 16 + r) * 32 + rq];
  };
  auto LDB = [&](int bbase, int bg) {
#pragma unroll
    for (int n2 = 0; n2 < 2; ++n2)
      Bf[bg][n2] = *(const short8*)
          &lds[bbase + (wc * 64 + bg * 32 + n2 * 16 + r) * 32 + rq];
  };
  auto MM = [&](int ag, int bg) {
#pragma unroll
    for (int m2 = 0; m2 < 4; ++m2)
#pragma unroll
      for (int n2 = 0; n2 < 2; ++n2)
        acc[ag * 4 + m2][bg * 2 + n2] =
            mfma32(Af[m2], Bf[bg][n2], acc[ag * 4 + m2][bg * 2 + n2]);
  };

  // prologue: A(0), B(0), A(1); wait A(0)+B(0) (A(1) stays in flight)
  STA(0); STB(0); STA(1);
  asm volatile("s_waitcnt vmcnt(2)" ::: "memory");
  __builtin_amdgcn_s_barrier();
  __builtin_amdgcn_sched_barrier(0);

#pragma unroll 1
  for (int i = 0; i < 16; ++i) {
    const int kc = 2 * i;
    const bool full = (i < 15);
    // ph1: kt kc (buf0), (A0,B0)
    LDA(0, 0); LDB(16384, 0);
    STB(kc + 1);
    BAR_IN(); MM(0, 0); BAR_OUT();
    // ph2: (A0,B1)
    LDB(16384, 1);
    BAR_IN(); MM(0, 1); BAR_OUT();
    // ph3: (A1,B1)
    LDA(0, 1);
    BAR_IN(); MM(1, 1); BAR_OUT();
    // ph4: (A1,B0); stage A(kc+2) (buf0-A reads retired at ph3);
    // vm completes A(kc+1)+B(kc+1) for ph5-7, leaves A(kc+2) in flight
    if (full) STA(kc + 2);
    BAR_IN(); MM(1, 0);
    if (full) { BAR_OUT_VM(2); } else { BAR_OUT_VM(0); }
    // ph5: kt kc+1 (buf1), (A0,B0); stage B(kc+2) (buf0-B reads done ph2)
    LDA(8192, 0); LDB(24576, 0);
    if (full) STB(kc + 2);
    BAR_IN(); MM(0, 0); BAR_OUT();
    // ph6: (A0,B1)
    LDB(24576, 1);
    BAR_IN(); MM(0, 1); BAR_OUT();
    // ph7: (A1,B1)
    LDA(8192, 1);
    BAR_IN(); MM(1, 1); BAR_OUT();
    // ph8: (A1,B0); stage A(kc+3) (buf1-A reads retired at ph7);
    // vm completes A(kc+2)+B(kc+2) for next ph1-3, leaves A(kc+3)
    if (full) {
      STA(kc + 3);
      BAR_IN(); MM(1, 0); BAR_OUT_VM(2);
    } else {
      BAR_IN(); MM(1, 0); BAR_OUT();
    }
  }

  // epilogue (verbatim from R7 -- absmax-verified)
  if (z == 2) {
    const int bq = m0 >> 11;
    const int hh = (n0 >> 6) + wc;
#pragma unroll
    for (int mi = 0; mi < 8; ++mi) {
      const int jt = ((m0 & 2047) >> 6) + wr * 2 + (mi >> 2);
      const int m3 = mi & 3;
      u16* vt_t = Vt + ((size_t)((bq * 16 + hh) * 32) + jt) * 4096;
      const int slot = (((q + 4 * (m3 >> 1)) ^ (r & 7)) * 8) + (m3 & 1) * 4;
#pragma unroll
      for (int ni = 0; ni < 4; ++ni) {
        short4v pk;
#pragma unroll
        for (int e = 0; e < 4; ++e) pk[e] = (short)f2bf(acc[mi][ni][e]);
        *(short4v*)&vt_t[(ni * 16 + r) * 64 + slot] = pk;
      }
    }
  } else {
    u16* __restrict__ Cb = z ? Ck : Cq;
#pragma unroll
    for (int mi = 0; mi < 8; ++mi) {
      const int row = m0 + wr * 128 + mi * 16 + q * 4;
#pragma unroll
      for (int ni = 0; ni < 4; ++ni) {
        const int col = n0 + wc * 64 + ni * 16 + r;
#pragma unroll
        for (int e = 0; e < 4; ++e)
          Cb[(size_t)(row + e) * 1024 + col] = f2bf(acc[mi][ni][e]);
      }
    }
  }
}

// ---------------------------------------------------------------------------
// Output GEMM (f32 out): unchanged 128x128 two-barrier BK=64 structure.
// ---------------------------------------------------------------------------
__global__ __launch_bounds__(256) void gemm_out(const u16* __restrict__ A,
                                                const u16* __restrict__ W,
                                                float* __restrict__ C) {
  __shared__ u16 Asm[128 * 64];
  __shared__ u16 Wsm[128 * 64];
  const int t = threadIdx.x;
  const int w = t >> 6, l = t & 63;
  const int wy = w >> 1, wx = w & 1;
  const int q = l >> 4, r = l & 15;
  const int m0 = blockIdx.x * 128, n0 = blockIdx.y * 128;

  f32x4 acc[4][4] = {};

  for (int k0 = 0; k0 < 1024; k0 += 64) {
    __syncthreads();
#pragma unroll
    for (int i = 0; i < 4; ++i) {
      const int c = t + i * 256;
      const int row = c >> 3, cl = c & 7;
      const int cg = cl ^ (row & 7);
      gl_lds16(A + (size_t)(m0 + row) * 1024 + k0 + cg * 8, &Asm[c * 8]);
      gl_lds16(W + (size_t)(n0 + row) * 1024 + k0 + cg * 8, &Wsm[c * 8]);
    }
    __syncthreads();
#pragma unroll
    for (int kf = 0; kf < 2; ++kf) {
      short8 af[4], bf[4];
#pragma unroll
      for (int mi = 0; mi < 4; ++mi) {
        const int rowA = wy * 64 + mi * 16 + r;
        af[mi] = *(const short8*)&Asm[rowA * 64 + ((kf * 4 + q) ^ (rowA & 7)) * 8];
        const int rowB = wx * 64 + mi * 16 + r;
        bf[mi] = *(const short8*)&Wsm[rowB * 64 + ((kf * 4 + q) ^ (rowB & 7)) * 8];
      }
#pragma unroll
      for (int mi = 0; mi < 4; ++mi)
#pragma unroll
        for (int ni = 0; ni < 4; ++ni)
          acc[mi][ni] = mfma32(af[mi], bf[ni], acc[mi][ni]);
    }
  }

#pragma unroll
  for (int mi = 0; mi < 4; ++mi) {
    const int row = m0 + wy * 64 + mi * 16 + q * 4;
#pragma unroll
    for (int ni = 0; ni < 4; ++ni) {
      const int col = n0 + wx * 64 + ni * 16 + r;
#pragma unroll
      for (int e = 0; e < 4; ++e)
        C[(size_t)(row + e) * 1024 + col] = acc[mi][ni][e];
    }
  }
}

// ---------------------------------------------------------------------------
// Flash attention v10, reverted VERBATIM from R6 (total 220.4 us config).
// v11's QBLK=128 regressed to 61.5 us: 1024-block grid left no backfill ->
// residency decayed to ~1.4 blocks/CU (occupancy 17.6%). v10's 2048-block
// grid keeps the 6 LDS slots/CU fed. LPT order, XCD pinning, K dbuf +
// single V buffer (24 KB), counted vmcnt(4) before PV, register softmax
// via S^T trick, PV via mfma32, setprio on MFMA.
// ---------------------------------------------------------------------------
__global__ __launch_bounds__(128) void attn_v10(const u16* __restrict__ Qb,
                                                const u16* __restrict__ Kb,
                                                const u16* __restrict__ Vt,
                                                u16* __restrict__ Ob) {
  const int i = blockIdx.x;                      // 0..2047
  const int st = 31 - (i >> 6);                  // heavy q-tiles first (LPT)
  const int grp = (i & 7) + 8 * ((i >> 3) & 7);  // (b,h) group, XCD-pinned
  const int b = grp >> 4, h = grp & 15;
  const int t = threadIdx.x;
  const int w = t >> 6, l = t & 63;
  const int q = l >> 4, r = l & 15;

  __shared__ u16 Kd[2][4096];   // K double buffer (16 KB)
  __shared__ u16 Vd[4096];      // V single buffer (8 KB)

  const size_t kgbase = (size_t)(b * Sn) * Dn + h * 64;
  const size_t vgbase = (size_t)((b * Hn + h) * 32) * 4096;

  const u16* kg[4];
  const u16* vg[4];
#pragma unroll
  for (int ii = 0; ii < 4; ++ii) {
    const int c = t + ii * 128, row = c >> 3, cl = c & 7;
    kg[ii] = Kb + kgbase + (size_t)row * Dn + (cl ^ (row & 7)) * 8;
    vg[ii] = Vt + vgbase + c * 8;
  }
  const int rx = r & 7;
  const int b0 = r * 64 + ((q ^ rx) * 8);
  const int b1 = r * 64 + (((4 + q) ^ rx) * 8);

  const int qb64 = st * 64;

  short8 Qf[2][2];
#pragma unroll
  for (int mi = 0; mi < 2; ++mi)
#pragma unroll
    for (int kf = 0; kf < 2; ++kf)
      Qf[mi][kf] = *(const short8*)(Qb +
          (size_t)(b * Sn + qb64 + w * 32 + mi * 16 + r) * Dn + h * 64 +
          kf * 32 + q * 8);

  f32x4 O[2][4] = {};
  float l_[2] = {0.f, 0.f};

#pragma unroll
  for (int ii = 0; ii < 4; ++ii)
    gl_lds16(kg[ii], &Kd[0][(t + ii * 128) * 8]);

  const u16* kgt[4];
  const u16* vgt[4];
#pragma unroll
  for (int ii = 0; ii < 4; ++ii) {
    kgt[ii] = kg[ii] + 64 * Dn;
    vgt[ii] = vg[ii];
  }

  for (int jt = 0; jt <= st; ++jt) {
    __syncthreads();  // vmcnt(0)+barrier: K(jt) staged; V(jt-1) reads done

#pragma unroll
    for (int ii = 0; ii < 4; ++ii) {
      gl_lds16(vgt[ii], &Vd[(t + ii * 128) * 8]);
      vgt[ii] += 4096;
    }
    if (jt < st) {
      u16* kl = &Kd[(jt + 1) & 1][0];
#pragma unroll
      for (int ii = 0; ii < 4; ++ii) {
        gl_lds16(kgt[ii], kl + (t + ii * 128) * 8);
        kgt[ii] += 64 * Dn;
      }
    }

    const u16* KtA = &Kd[jt & 1][b0];
    const u16* KtB = &Kd[jt & 1][b1];

    short8 Kf[4][2];
#pragma unroll
    for (int ni = 0; ni < 4; ++ni) {
      Kf[ni][0] = *(const short8*)(KtA + ni * 1024);
      Kf[ni][1] = *(const short8*)(KtB + ni * 1024);
    }

    f32x4 S[2][4] = {};
    __builtin_amdgcn_s_setprio(1);
#pragma unroll
    for (int ni = 0; ni < 4; ++ni)
#pragma unroll
      for (int kf = 0; kf < 2; ++kf) {
        S[0][ni] = mfma32(Kf[ni][kf], Qf[0][kf], S[0][ni]);
        S[1][ni] = mfma32(Kf[ni][kf], Qf[1][kf], S[1][ni]);
      }
    __builtin_amdgcn_s_setprio(0);

    if (jt == st) {
#pragma unroll
      for (int mi = 0; mi < 2; ++mi) {
        const int qrow = w * 32 + mi * 16 + r;
#pragma unroll
        for (int ni = 0; ni < 4; ++ni) {
          const int key = ni * 16 + q * 4;
#pragma unroll
          for (int e = 0; e < 4; ++e)
            if (key + e > qrow) S[mi][ni][e] = -3.0e38f;
        }
      }
    }

    short8 P8[2][2];
#pragma unroll
    for (int mi = 0; mi < 2; ++mi)
#pragma unroll
      for (int np = 0; np < 2; ++np) {
        unsigned pw[4];
#pragma unroll
        for (int half = 0; half < 2; ++half) {
          const int ni = 2 * np + half;
          const float p0 = __builtin_amdgcn_exp2f(S[mi][ni][0]);
          const float p1 = __builtin_amdgcn_exp2f(S[mi][ni][1]);
          const float p2 = __builtin_amdgcn_exp2f(S[mi][ni][2]);
          const float p3 = __builtin_amdgcn_exp2f(S[mi][ni][3]);
          l_[mi] += (p0 + p1) + (p2 + p3);
          unsigned plo, phi;
          asm("v_cvt_pk_bf16_f32 %0, %1, %2" : "=v"(plo) : "v"(p0), "v"(p1));
          asm("v_cvt_pk_bf16_f32 %0, %1, %2" : "=v"(phi) : "v"(p2), "v"(p3));
          pw[half * 2] = plo;
          pw[half * 2 + 1] = phi;
        }
        const uint4v pk4 = {pw[0], pw[1], pw[2], pw[3]};
        P8[mi][np] = __builtin_bit_cast(short8, pk4);
      }

    if (jt < st)
      asm volatile("s_waitcnt vmcnt(4)" ::: "memory");
    else
      asm volatile("s_waitcnt vmcnt(0)" ::: "memory");
    __builtin_amdgcn_s_barrier();
    __builtin_amdgcn_sched_barrier(0);

    __builtin_amdgcn_s_setprio(1);
#pragma unroll
    for (int np = 0; np < 2; ++np) {
      const int vb = np ? b1 : b0;
#pragma unroll
      for (int ni2 = 0; ni2 < 4; ++ni2) {
        const short8 vvx = *(const short8*)(&Vd[vb + ni2 * 1024]);
        O[0][ni2] = mfma32(vvx, P8[0][np], O[0][ni2]);
        O[1][ni2] = mfma32(vvx, P8[1][np], O[1][ni2]);
      }
    }
    __builtin_amdgcn_s_setprio(0);
  }

#pragma unroll
  for (int mi = 0; mi < 2; ++mi) {
    float s = l_[mi];
    s += __shfl_xor(s, 16, 64);
    s += __shfl_xor(s, 32, 64);
    const float rl = __builtin_amdgcn_rcpf(s);
#pragma unroll
    for (int ni2 = 0; ni2 < 4; ++ni2) {
      short4v o;
#pragma unroll
      for (int e = 0; e < 4; ++e) o[e] = (short)f2bf(O[mi][ni2][e] * rl);
      *(short4v*)(Ob + (size_t)(b * Sn + qb64 + w * 32 + mi * 16 + r) * Dn +
                  h * 64 + ni2 * 16 + q * 4) = o;
    }
  }
}

// ---------------------------------------------------------------------------
extern "C" void kernel_launch(void* const* d_in, const int* in_sizes, int n_in,
                              void* d_out, int out_size, void* d_ws, size_t ws_size,
                              hipStream_t stream) {
  const float* x  = (const float*)d_in[0];
  const float* wq = (const float*)d_in[1];
  const float* wk = (const float*)d_in[2];
  const float* wv = (const float*)d_in[3];
  const float* wo = (const float*)d_in[4];
  float* out = (float*)d_out;

  u16* xb  = (u16*)d_ws;            // 8M u16
  u16* wqb = xb + 8388608;
  u16* wkb = wqb + 1048576;
  u16* wvb = wkb + 1048576;
  u16* wob = wvb + 1048576;
  u16* qb  = wob + 1048576;         // 8M each
  u16* kb  = qb + 8388608;
  u16* vt2 = kb + 8388608;          // V^T tiles, pre-swizzled
  u16* aob = vt2 + 8388608;

  cast_all<<<12288, 256, 0, stream>>>(
      (const float4*)x, (const float4*)wq, (const float4*)wk,
      (const float4*)wv, (const float4*)wo, (ushort4*)xb, (ushort4*)wqb,
      (ushort4*)wkb, (ushort4*)wvb, (ushort4*)wob);

  gemm_qkv8<<<dim3(32, 4, 3), 512, 0, stream>>>(xb, wqb, wkb, wvb, qb, kb, vt2);

  attn_v10<<<2048, 128, 0, stream>>>(qb, kb, vt2, aob);

  gemm_out<<<dim3(64, 8), 256, 0, stream>>>(aob, wob, out);
}

// Round 11
// 234.177 us; speedup vs baseline: 1.0106x; 1.0106x over previous
//
#include <hip/hip_runtime.h>
#include <math.h>

typedef unsigned short u16;
typedef __attribute__((ext_vector_type(8))) short short8;   // 8 bf16 = 4 VGPRs
typedef __attribute__((ext_vector_type(4))) short short4v;  // 4 bf16 = 2 VGPRs
typedef __attribute__((ext_vector_type(4))) float f32x4;    // MFMA C/D frag
typedef __attribute__((ext_vector_type(4))) unsigned int uint4v;

constexpr int Bn = 4, Sn = 2048, Dn = 1024, Hn = 16;
constexpr float SCL = 0.125f * 1.44269504f;  // 1/sqrt(64) * log2(e), folded into Wq

__device__ __forceinline__ u16 f2bf(float f) {  // RNE float->bf16
  unsigned u = __float_as_uint(f);
  u += 0x7fffu + ((u >> 16) & 1u);
  return (u16)(u >> 16);
}

__device__ __forceinline__ f32x4 mfma32(short8 a, short8 b, f32x4 c) {
  return __builtin_amdgcn_mfma_f32_16x16x32_bf16(a, b, c, 0, 0, 0);
}

__device__ __forceinline__ void gl_lds16(const u16* g, u16* l) {
  __builtin_amdgcn_global_load_lds(
      (const __attribute__((address_space(1))) unsigned int*)g,
      (__attribute__((address_space(3))) unsigned int*)l, 16, 0, 0);
}

// Barrier brackets for the 8-phase schedule (R7-verified): sched_barrier(0)
// on both sides of every s_barrier pins program order (rule #18 family).
#define BAR_IN()                                          \
  do {                                                    \
    __builtin_amdgcn_sched_barrier(0);                    \
    __builtin_amdgcn_s_barrier();                         \
    asm volatile("s_waitcnt lgkmcnt(0)" ::: "memory");    \
    __builtin_amdgcn_sched_barrier(0);                    \
    __builtin_amdgcn_s_setprio(1);                        \
  } while (0)
#define BAR_OUT()                                         \
  do {                                                    \
    __builtin_amdgcn_s_setprio(0);                        \
    __builtin_amdgcn_sched_barrier(0);                    \
    __builtin_amdgcn_s_barrier();                         \
    __builtin_amdgcn_sched_barrier(0);                    \
  } while (0)
#define BAR_OUT_VM(N)                                     \
  do {                                                    \
    __builtin_amdgcn_s_setprio(0);                        \
    __builtin_amdgcn_sched_barrier(0);                    \
    asm volatile("s_waitcnt vmcnt(" #N ")" ::: "memory"); \
    __builtin_amdgcn_s_barrier();                         \
    __builtin_amdgcn_sched_barrier(0);                    \
  } while (0)

// ---------------------------------------------------------------------------
// One launch for all f32->bf16 casts. Blocks 0..8191: x. Then 1024 each for
// wq (pre-scaled by SCL), wk, wv, wo.
// ---------------------------------------------------------------------------
__global__ __launch_bounds__(256) void cast_all(
    const float4* __restrict__ x, const float4* __restrict__ wq,
    const float4* __restrict__ wk, const float4* __restrict__ wv,
    const float4* __restrict__ wo, ushort4* __restrict__ xb,
    ushort4* __restrict__ wqb, ushort4* __restrict__ wkb,
    ushort4* __restrict__ wvb, ushort4* __restrict__ wob) {
  const int blk = blockIdx.x;
  const float4* in;
  ushort4* out;
  int base;
  float s = 1.0f;
  if (blk < 8192) {
    in = x; out = xb; base = blk;
  } else if (blk < 9216) {
    in = wq; out = wqb; base = blk - 8192; s = SCL;
  } else if (blk < 10240) {
    in = wk; out = wkb; base = blk - 9216;
  } else if (blk < 11264) {
    in = wv; out = wvb; base = blk - 10240;
  } else {
    in = wo; out = wob; base = blk - 11264;
  }
  const int i = base * 256 + threadIdx.x;
  const float4 f = in[i];
  ushort4 o;
  o.x = f2bf(f.x * s); o.y = f2bf(f.y * s);
  o.z = f2bf(f.z * s); o.w = f2bf(f.w * s);
  out[i] = o;
}

// ---------------------------------------------------------------------------
// QKV GEMM, 256x256 tile, BK=32, 8 waves, 8-phase counted-vmcnt schedule.
// R10 measured 73.4 us with SQ_LDS_BANK_CONFLICT = 4.7M (all prior GEMMs: 0)
// -- the BK=32 row is 64 B (4 chunks), and the old cl^(row&3) swizzle left
// consecutive-8-lane read phases 2-way aliased (lanes r, r+4 same 4-bank
// slot) => every ds_read_b128 at 2x its 8-cy floor inside the per-phase
// lgkmcnt(0). FIX: row-PAIR (128 B) is the 8-slot swizzle unit.
//   slot s  <->  (row = 2*(s>>3) + (u>>2), chunk = u&3), u = (s&7)^((s>>3)&7)
//   read (row,q) at  pair*64 + ((q + 4*(row&1)) ^ (pair&7))*8   [u16 units]
// Verified: each consecutive 8-lane group covers slots {q^p, q^p^4, p=0..3}
// = all 8 => 32 banks, conflict-free; all A/B frag bases have (base>>1)&7=0.
// LDS u16[32768] (64 KB, 2 blocks/CU, 384 blocks = ONE dispatch round):
// A bufs @0/8192, B bufs @16384/24576. Stage stream per iter (kc=2i):
// ph1: B(kc+1), ph4: A(kc+2), ph5: B(kc+2), ph8: A(kc+3); vmcnt(2) at
// ph4/ph8 only. Buffer-overwrite hazards covered by the two barriers per
// phase (a wave issues a stage only after the prior phase's BAR_OUT, which
// requires all waves' reads of that buffer to have completed).
// ---------------------------------------------------------------------------
__global__ __launch_bounds__(512, 2) void gemm_qkv8(
    const u16* __restrict__ A, const u16* __restrict__ Wq,
    const u16* __restrict__ Wk, const u16* __restrict__ Wv,
    u16* __restrict__ Cq, u16* __restrict__ Ck, u16* __restrict__ Vt) {
  __shared__ u16 lds[32768];  // 64 KB

  const int t = threadIdx.x;
  const int w8 = t >> 6, l = t & 63;
  const int wr = w8 >> 2, wc = w8 & 3;      // wave grid 2M x 4N
  const int q = l >> 4, r = l & 15;
  const int m0 = blockIdx.x * 256, n0 = blockIdx.y * 256;
  const int z = blockIdx.z;
  const u16* __restrict__ W = z == 0 ? Wq : z == 1 ? Wk : Wv;

  // Stage sources: LDS slot s = t + ii*512 (lane-linear dest, gl_lds
  // requirement). Inverse of the pair-swizzle gives the global (row, chunk):
  //   pr = s>>3, u = (s&7) ^ (pr&7), row = 2*pr + (u>>2), c = u&3.
  const u16* asrc[2];
  const u16* wsrc[2];
#pragma unroll
  for (int ii = 0; ii < 2; ++ii) {
    const int s = t + ii * 512;
    const int pr = s >> 3;
    const int u = (s & 7) ^ (pr & 7);
    const int row = pr * 2 + (u >> 2), c = u & 3;
    asrc[ii] = A + (size_t)(m0 + row) * 1024 + c * 8;
    wsrc[ii] = W + (size_t)(n0 + row) * 1024 + c * 8;
  }

  auto STA = [&](int kt) {
#pragma unroll
    for (int ii = 0; ii < 2; ++ii)
      gl_lds16(asrc[ii] + kt * 32, &lds[(kt & 1) * 8192 + t * 8 + ii * 4096]);
  };
  auto STB = [&](int kt) {
#pragma unroll
    for (int ii = 0; ii < 2; ++ii)
      gl_lds16(wsrc[ii] + kt * 32,
               &lds[16384 + (kt & 1) * 8192 + t * 8 + ii * 4096]);
  };

  f32x4 acc[8][4] = {};
  short8 Af[4];      // current A quadrant (4 m2), K=32 -> 1 frag each
  short8 Bf[2][2];   // both B groups persist across phases

  // Read-side pair swizzle: pair = r>>1 (base contributes 0 mod 8),
  // slot = (q + 4*(r&1)) ^ (r>>1).
  const int pa = r >> 1;
  const int rsw = ((q + 4 * (r & 1)) ^ pa) * 8;
  const int roff = pa * 64 + rsw;  // per-lane read offset within frag row-grp
  auto LDA = [&](int abase, int ag) {
    const int rb = abase + (wr * 128 + ag * 64) * 32 + roff;
#pragma unroll
    for (int m2 = 0; m2 < 4; ++m2)
      Af[m2] = *(const short8*)&lds[rb + m2 * 512];
  };
  auto LDB = [&](int bbase, int bg) {
    const int rb = bbase + (wc * 64 + bg * 32) * 32 + roff;
#pragma unroll
    for (int n2 = 0; n2 < 2; ++n2)
      Bf[bg][n2] = *(const short8*)&lds[rb + n2 * 512];
  };
  auto MM = [&](int ag, int bg) {
#pragma unroll
    for (int m2 = 0; m2 < 4; ++m2)
#pragma unroll
      for (int n2 = 0; n2 < 2; ++n2)
        acc[ag * 4 + m2][bg * 2 + n2] =
            mfma32(Af[m2], Bf[bg][n2], acc[ag * 4 + m2][bg * 2 + n2]);
  };

  // prologue: A(0), B(0), A(1); wait A(0)+B(0) (A(1) stays in flight)
  STA(0); STB(0); STA(1);
  asm volatile("s_waitcnt vmcnt(2)" ::: "memory");
  __builtin_amdgcn_s_barrier();
  __builtin_amdgcn_sched_barrier(0);

#pragma unroll 1
  for (int i = 0; i < 16; ++i) {
    const int kc = 2 * i;
    const bool full = (i < 15);
    // ph1: kt kc (buf0), (A0,B0)
    LDA(0, 0); LDB(16384, 0);
    STB(kc + 1);
    BAR_IN(); MM(0, 0); BAR_OUT();
    // ph2: (A0,B1)
    LDB(16384, 1);
    BAR_IN(); MM(0, 1); BAR_OUT();
    // ph3: (A1,B1)
    LDA(0, 1);
    BAR_IN(); MM(1, 1); BAR_OUT();
    // ph4: (A1,B0); stage A(kc+2) (buf0-A reads retired at ph3's BAR_OUT);
    // vm completes A(kc+1)+B(kc+1) for ph5-7, leaves A(kc+2) in flight
    if (full) STA(kc + 2);
    BAR_IN(); MM(1, 0);
    if (full) { BAR_OUT_VM(2); } else { BAR_OUT_VM(0); }
    // ph5: kt kc+1 (buf1), (A0,B0); stage B(kc+2) (buf0-B reads done ph2)
    LDA(8192, 0); LDB(24576, 0);
    if (full) STB(kc + 2);
    BAR_IN(); MM(0, 0); BAR_OUT();
    // ph6: (A0,B1)
    LDB(24576, 1);
    BAR_IN(); MM(0, 1); BAR_OUT();
    // ph7: (A1,B1)
    LDA(8192, 1);
    BAR_IN(); MM(1, 1); BAR_OUT();
    // ph8: (A1,B0); stage A(kc+3) (buf1-A reads retired at ph7's BAR_OUT);
    // vm completes A(kc+2)+B(kc+2) for next ph1-3, leaves A(kc+3)
    if (full) {
      STA(kc + 3);
      BAR_IN(); MM(1, 0); BAR_OUT_VM(2);
    } else {
      BAR_IN(); MM(1, 0); BAR_OUT();
    }
  }

  // epilogue (verbatim from R7 -- absmax-verified)
  if (z == 2) {
    const int bq = m0 >> 11;
    const int hh = (n0 >> 6) + wc;
#pragma unroll
    for (int mi = 0; mi < 8; ++mi) {
      const int jt = ((m0 & 2047) >> 6) + wr * 2 + (mi >> 2);
      const int m3 = mi & 3;
      u16* vt_t = Vt + ((size_t)((bq * 16 + hh) * 32) + jt) * 4096;
      const int slot = (((q + 4 * (m3 >> 1)) ^ (r & 7)) * 8) + (m3 & 1) * 4;
#pragma unroll
      for (int ni = 0; ni < 4; ++ni) {
        short4v pk;
#pragma unroll
        for (int e = 0; e < 4; ++e) pk[e] = (short)f2bf(acc[mi][ni][e]);
        *(short4v*)&vt_t[(ni * 16 + r) * 64 + slot] = pk;
      }
    }
  } else {
    u16* __restrict__ Cb = z ? Ck : Cq;
#pragma unroll
    for (int mi = 0; mi < 8; ++mi) {
      const int row = m0 + wr * 128 + mi * 16 + q * 4;
#pragma unroll
      for (int ni = 0; ni < 4; ++ni) {
        const int col = n0 + wc * 64 + ni * 16 + r;
#pragma unroll
        for (int e = 0; e < 4; ++e)
          Cb[(size_t)(row + e) * 1024 + col] = f2bf(acc[mi][ni][e]);
      }
    }
  }
}

// ---------------------------------------------------------------------------
// Output GEMM (f32 out): unchanged 128x128 two-barrier BK=64 structure.
// ---------------------------------------------------------------------------
__global__ __launch_bounds__(256) void gemm_out(const u16* __restrict__ A,
                                                const u16* __restrict__ W,
                                                float* __restrict__ C) {
  __shared__ u16 Asm[128 * 64];
  __shared__ u16 Wsm[128 * 64];
  const int t = threadIdx.x;
  const int w = t >> 6, l = t & 63;
  const int wy = w >> 1, wx = w & 1;
  const int q = l >> 4, r = l & 15;
  const int m0 = blockIdx.x * 128, n0 = blockIdx.y * 128;

  f32x4 acc[4][4] = {};

  for (int k0 = 0; k0 < 1024; k0 += 64) {
    __syncthreads();
#pragma unroll
    for (int i = 0; i < 4; ++i) {
      const int c = t + i * 256;
      const int row = c >> 3, cl = c & 7;
      const int cg = cl ^ (row & 7);
      gl_lds16(A + (size_t)(m0 + row) * 1024 + k0 + cg * 8, &Asm[c * 8]);
      gl_lds16(W + (size_t)(n0 + row) * 1024 + k0 + cg * 8, &Wsm[c * 8]);
    }
    __syncthreads();
#pragma unroll
    for (int kf = 0; kf < 2; ++kf) {
      short8 af[4], bf[4];
#pragma unroll
      for (int mi = 0; mi < 4; ++mi) {
        const int rowA = wy * 64 + mi * 16 + r;
        af[mi] = *(const short8*)&Asm[rowA * 64 + ((kf * 4 + q) ^ (rowA & 7)) * 8];
        const int rowB = wx * 64 + mi * 16 + r;
        bf[mi] = *(const short8*)&Wsm[rowB * 64 + ((kf * 4 + q) ^ (rowB & 7)) * 8];
      }
#pragma unroll
      for (int mi = 0; mi < 4; ++mi)
#pragma unroll
        for (int ni = 0; ni < 4; ++ni)
          acc[mi][ni] = mfma32(af[mi], bf[ni], acc[mi][ni]);
    }
  }

#pragma unroll
  for (int mi = 0; mi < 4; ++mi) {
    const int row = m0 + wy * 64 + mi * 16 + q * 4;
#pragma unroll
    for (int ni = 0; ni < 4; ++ni) {
      const int col = n0 + wx * 64 + ni * 16 + r;
#pragma unroll
      for (int e = 0; e < 4; ++e)
        C[(size_t)(row + e) * 1024 + col] = acc[mi][ni][e];
    }
  }
}

// ---------------------------------------------------------------------------
// Flash attention v10 (unchanged; R6-verified): LPT order, XCD pinning,
// K dbuf + single V buffer (24 KB), counted vmcnt(4) before PV, register
// softmax via S^T trick, PV via mfma32, setprio on MFMA.
// ---------------------------------------------------------------------------
__global__ __launch_bounds__(128) void attn_v10(const u16* __restrict__ Qb,
                                                const u16* __restrict__ Kb,
                                                const u16* __restrict__ Vt,
                                                u16* __restrict__ Ob) {
  const int i = blockIdx.x;                      // 0..2047
  const int st = 31 - (i >> 6);                  // heavy q-tiles first (LPT)
  const int grp = (i & 7) + 8 * ((i >> 3) & 7);  // (b,h) group, XCD-pinned
  const int b = grp >> 4, h = grp & 15;
  const int t = threadIdx.x;
  const int w = t >> 6, l = t & 63;
  const int q = l >> 4, r = l & 15;

  __shared__ u16 Kd[2][4096];   // K double buffer (16 KB)
  __shared__ u16 Vd[4096];      // V single buffer (8 KB)

  const size_t kgbase = (size_t)(b * Sn) * Dn + h * 64;
  const size_t vgbase = (size_t)((b * Hn + h) * 32) * 4096;

  const u16* kg[4];
  const u16* vg[4];
#pragma unroll
  for (int ii = 0; ii < 4; ++ii) {
    const int c = t + ii * 128, row = c >> 3, cl = c & 7;
    kg[ii] = Kb + kgbase + (size_t)row * Dn + (cl ^ (row & 7)) * 8;
    vg[ii] = Vt + vgbase + c * 8;
  }
  const int rx = r & 7;
  const int b0 = r * 64 + ((q ^ rx) * 8);
  const int b1 = r * 64 + (((4 + q) ^ rx) * 8);

  const int qb64 = st * 64;

  short8 Qf[2][2];
#pragma unroll
  for (int mi = 0; mi < 2; ++mi)
#pragma unroll
    for (int kf = 0; kf < 2; ++kf)
      Qf[mi][kf] = *(const short8*)(Qb +
          (size_t)(b * Sn + qb64 + w * 32 + mi * 16 + r) * Dn + h * 64 +
          kf * 32 + q * 8);

  f32x4 O[2][4] = {};
  float l_[2] = {0.f, 0.f};

#pragma unroll
  for (int ii = 0; ii < 4; ++ii)
    gl_lds16(kg[ii], &Kd[0][(t + ii * 128) * 8]);

  const u16* kgt[4];
  const u16* vgt[4];
#pragma unroll
  for (int ii = 0; ii < 4; ++ii) {
    kgt[ii] = kg[ii] + 64 * Dn;
    vgt[ii] = vg[ii];
  }

  for (int jt = 0; jt <= st; ++jt) {
    __syncthreads();  // vmcnt(0)+barrier: K(jt) staged; V(jt-1) reads done

#pragma unroll
    for (int ii = 0; ii < 4; ++ii) {
      gl_lds16(vgt[ii], &Vd[(t + ii * 128) * 8]);
      vgt[ii] += 4096;
    }
    if (jt < st) {
      u16* kl = &Kd[(jt + 1) & 1][0];
#pragma unroll
      for (int ii = 0; ii < 4; ++ii) {
        gl_lds16(kgt[ii], kl + (t + ii * 128) * 8);
        kgt[ii] += 64 * Dn;
      }
    }

    const u16* KtA = &Kd[jt & 1][b0];
    const u16* KtB = &Kd[jt & 1][b1];

    short8 Kf[4][2];
#pragma unroll
    for (int ni = 0; ni < 4; ++ni) {
      Kf[ni][0] = *(const short8*)(KtA + ni * 1024);
      Kf[ni][1] = *(const short8*)(KtB + ni * 1024);
    }

    f32x4 S[2][4] = {};
    __builtin_amdgcn_s_setprio(1);
#pragma unroll
    for (int ni = 0; ni < 4; ++ni)
#pragma unroll
      for (int kf = 0; kf < 2; ++kf) {
        S[0][ni] = mfma32(Kf[ni][kf], Qf[0][kf], S[0][ni]);
        S[1][ni] = mfma32(Kf[ni][kf], Qf[1][kf], S[1][ni]);
      }
    __builtin_amdgcn_s_setprio(0);

    if (jt == st) {
#pragma unroll
      for (int mi = 0; mi < 2; ++mi) {
        const int qrow = w * 32 + mi * 16 + r;
#pragma unroll
        for (int ni = 0; ni < 4; ++ni) {
          const int key = ni * 16 + q * 4;
#pragma unroll
          for (int e = 0; e < 4; ++e)
            if (key + e > qrow) S[mi][ni][e] = -3.0e38f;
        }
      }
    }

    short8 P8[2][2];
#pragma unroll
    for (int mi = 0; mi < 2; ++mi)
#pragma unroll
      for (int np = 0; np < 2; ++np) {
        unsigned pw[4];
#pragma unroll
        for (int half = 0; half < 2; ++half) {
          const int ni = 2 * np + half;
          const float p0 = __builtin_amdgcn_exp2f(S[mi][ni][0]);
          const float p1 = __builtin_amdgcn_exp2f(S[mi][ni][1]);
          const float p2 = __builtin_amdgcn_exp2f(S[mi][ni][2]);
          const float p3 = __builtin_amdgcn_exp2f(S[mi][ni][3]);
          l_[mi] += (p0 + p1) + (p2 + p3);
          unsigned plo, phi;
          asm("v_cvt_pk_bf16_f32 %0, %1, %2" : "=v"(plo) : "v"(p0), "v"(p1));
          asm("v_cvt_pk_bf16_f32 %0, %1, %2" : "=v"(phi) : "v"(p2), "v"(p3));
          pw[half * 2] = plo;
          pw[half * 2 + 1] = phi;
        }
        const uint4v pk4 = {pw[0], pw[1], pw[2], pw[3]};
        P8[mi][np] = __builtin_bit_cast(short8, pk4);
      }

    if (jt < st)
      asm volatile("s_waitcnt vmcnt(4)" ::: "memory");
    else
      asm volatile("s_waitcnt vmcnt(0)" ::: "memory");
    __builtin_amdgcn_s_barrier();
    __builtin_amdgcn_sched_barrier(0);

    __builtin_amdgcn_s_setprio(1);
#pragma unroll
    for (int np = 0; np < 2; ++np) {
      const int vb = np ? b1 : b0;
#pragma unroll
      for (int ni2 = 0; ni2 < 4; ++ni2) {
        const short8 vvx = *(const short8*)(&Vd[vb + ni2 * 1024]);
        O[0][ni2] = mfma32(vvx, P8[0][np], O[0][ni2]);
        O[1][ni2] = mfma32(vvx, P8[1][np], O[1][ni2]);
      }
    }
    __builtin_amdgcn_s_setprio(0);
  }

#pragma unroll
  for (int mi = 0; mi < 2; ++mi) {
    float s = l_[mi];
    s += __shfl_xor(s, 16, 64);
    s += __shfl_xor(s, 32, 64);
    const float rl = __builtin_amdgcn_rcpf(s);
#pragma unroll
    for (int ni2 = 0; ni2 < 4; ++ni2) {
      short4v o;
#pragma unroll
      for (int e = 0; e < 4; ++e) o[e] = (short)f2bf(O[mi][ni2][e] * rl);
      *(short4v*)(Ob + (size_t)(b * Sn + qb64 + w * 32 + mi * 16 + r) * Dn +
                  h * 64 + ni2 * 16 + q * 4) = o;
    }
  }
}

// ---------------------------------------------------------------------------
extern "C" void kernel_launch(void* const* d_in, const int* in_sizes, int n_in,
                              void* d_out, int out_size, void* d_ws, size_t ws_size,
                              hipStream_t stream) {
  const float* x  = (const float*)d_in[0];
  const float* wq = (const float*)d_in[1];
  const float* wk = (const float*)d_in[2];
  const float* wv = (const float*)d_in[3];
  const float* wo = (const float*)d_in[4];
  float* out = (float*)d_out;

  u16* xb  = (u16*)d_ws;            // 8M u16
  u16* wqb = xb + 8388608;
  u16* wkb = wqb + 1048576;
  u16* wvb = wkb + 1048576;
  u16* wob = wvb + 1048576;
  u16* qb  = wob + 1048576;         // 8M each
  u16* kb  = qb + 8388608;
  u16* vt2 = kb + 8388608;          // V^T tiles, pre-swizzled
  u16* aob = vt2 + 8388608;

  cast_all<<<12288, 256, 0, stream>>>(
      (const float4*)x, (const float4*)wq, (const float4*)wk,
      (const float4*)wv, (const float4*)wo, (ushort4*)xb, (ushort4*)wqb,
      (ushort4*)wkb, (ushort4*)wvb, (ushort4*)wob);

  gemm_qkv8<<<dim3(32, 4, 3), 512, 0, stream>>>(xb, wqb, wkb, wvb, qb, kb, vt2);

  attn_v10<<<2048, 128, 0, stream>>>(qb, kb, vt2, aob);

  gemm_out<<<dim3(64, 8), 256, 0, stream>>>(aob, wob, out);
}

// Round 12
// 232.739 us; speedup vs baseline: 1.0168x; 1.0062x over previous
//
#include <hip/hip_runtime.h>
#include <math.h>

typedef unsigned short u16;
typedef __attribute__((ext_vector_type(8))) short short8;   // 8 bf16 = 4 VGPRs
typedef __attribute__((ext_vector_type(4))) short short4v;  // 4 bf16 = 2 VGPRs
typedef __attribute__((ext_vector_type(4))) float f32x4;    // MFMA C/D frag
typedef __attribute__((ext_vector_type(4))) unsigned int uint4v;

constexpr int Bn = 4, Sn = 2048, Dn = 1024, Hn = 16;
constexpr float SCL = 0.125f * 1.44269504f;  // 1/sqrt(64) * log2(e), folded into Wq

__device__ __forceinline__ u16 f2bf(float f) {  // RNE float->bf16
  unsigned u = __float_as_uint(f);
  u += 0x7fffu + ((u >> 16) & 1u);
  return (u16)(u >> 16);
}

__device__ __forceinline__ f32x4 mfma32(short8 a, short8 b, f32x4 c) {
  return __builtin_amdgcn_mfma_f32_16x16x32_bf16(a, b, c, 0, 0, 0);
}

__device__ __forceinline__ void gl_lds16(const u16* g, u16* l) {
  __builtin_amdgcn_global_load_lds(
      (const __attribute__((address_space(1))) unsigned int*)g,
      (__attribute__((address_space(3))) unsigned int*)l, 16, 0, 0);
}

// ---------------------------------------------------------------------------
// One launch for all f32->bf16 casts. Blocks 0..8191: x. Then 1024 each for
// wq (pre-scaled by SCL), wk, wv, wo.
// ---------------------------------------------------------------------------
__global__ __launch_bounds__(256) void cast_all(
    const float4* __restrict__ x, const float4* __restrict__ wq,
    const float4* __restrict__ wk, const float4* __restrict__ wv,
    const float4* __restrict__ wo, ushort4* __restrict__ xb,
    ushort4* __restrict__ wqb, ushort4* __restrict__ wkb,
    ushort4* __restrict__ wvb, ushort4* __restrict__ wob) {
  const int blk = blockIdx.x;
  const float4* in;
  ushort4* out;
  int base;
  float s = 1.0f;
  if (blk < 8192) {
    in = x; out = xb; base = blk;
  } else if (blk < 9216) {
    in = wq; out = wqb; base = blk - 8192; s = SCL;
  } else if (blk < 10240) {
    in = wk; out = wkb; base = blk - 9216;
  } else if (blk < 11264) {
    in = wv; out = wvb; base = blk - 10240;
  } else {
    in = wo; out = wob; base = blk - 11264;
  }
  const int i = base * 256 + threadIdx.x;
  const float4 f = in[i];
  ushort4 o;
  o.x = f2bf(f.x * s); o.y = f2bf(f.y * s);
  o.z = f2bf(f.z * s); o.w = f2bf(f.w * s);
  out[i] = o;
}

// ---------------------------------------------------------------------------
// QKV GEMM: 128x128 tile, BK=64, 4 waves, m97 two-barrier structure --
// session-proven 60.6 us for all 3 slices (R6). The 8-phase 256-sq line is
// CLOSED: BK=64 variant lost to 1-block/CU grid quantization (R7, 69.2);
// BK=32 variant with conflict-free pair-swizzle (R11, bank conflicts 0)
// still 69.0 -- 128 phases x 2-barriers with only 8 MFMA each is
// barrier-dominated at this problem size. LDS at kernel scope (shared by
// both instantiations). Swizzle cl^(row&7), conflict-free (counters: 0).
// MODE 0: bf16 natural; MODE 2: bf16 into vt2 = V^T tiles [hd][key]
// (64x64 per (b,h,jt)), 16B chunks XOR-swizzled by hd.
// ---------------------------------------------------------------------------
template <int MODE>
__device__ __forceinline__ void gemm_body(const u16* __restrict__ A,
                                          const u16* __restrict__ W,
                                          u16* __restrict__ Cb,
                                          int bx, int by,
                                          u16* __restrict__ Asm,
                                          u16* __restrict__ Wsm) {
  const int t = threadIdx.x;
  const int w = t >> 6, l = t & 63;
  const int wy = w >> 1, wx = w & 1;
  const int q = l >> 4, r = l & 15;
  const int m0 = bx * 128, n0 = by * 128;

  f32x4 acc[4][4] = {};

  for (int k0 = 0; k0 < 1024; k0 += 64) {
    __syncthreads();
#pragma unroll
    for (int i = 0; i < 4; ++i) {
      const int c = t + i * 256;            // 16B chunk id, 0..1023
      const int row = c >> 3, cl = c & 7;   // 8 chunks per 128B row
      const int cg = cl ^ (row & 7);        // pre-swizzled global source
      gl_lds16(A + (size_t)(m0 + row) * 1024 + k0 + cg * 8, &Asm[c * 8]);
      gl_lds16(W + (size_t)(n0 + row) * 1024 + k0 + cg * 8, &Wsm[c * 8]);
    }
    __syncthreads();
#pragma unroll
    for (int kf = 0; kf < 2; ++kf) {
      short8 af[4], bf[4];
#pragma unroll
      for (int mi = 0; mi < 4; ++mi) {
        const int rowA = wy * 64 + mi * 16 + r;
        af[mi] = *(const short8*)&Asm[rowA * 64 + ((kf * 4 + q) ^ (rowA & 7)) * 8];
        const int rowB = wx * 64 + mi * 16 + r;
        bf[mi] = *(const short8*)&Wsm[rowB * 64 + ((kf * 4 + q) ^ (rowB & 7)) * 8];
      }
#pragma unroll
      for (int mi = 0; mi < 4; ++mi)
#pragma unroll
        for (int ni = 0; ni < 4; ++ni)
          acc[mi][ni] = mfma32(af[mi], bf[ni], acc[mi][ni]);
    }
  }

  if (MODE == 2) {
    // acc[mi][ni][e]: token = m0+wy*64+mi*16+q*4+e, feat = n0+wx*64+ni*16+r.
    // -> vt2 tile (b, h, jt): V^T[hd=ni*16+r][key=mi*16+q*4+e], stored as
    // 16B chunks c2 = q + 4*(mi>>1) at slot c2^(hd&7), half (mi&1).
    const int bq = m0 >> 11;
    const int jt = ((m0 & 2047) >> 6) + wy;
    const int hh = (n0 >> 6) + wx;
    u16* vt_t = Cb + ((size_t)((bq * 16 + hh) * 32) + jt) * 4096;
#pragma unroll
    for (int mi = 0; mi < 4; ++mi)
#pragma unroll
      for (int ni = 0; ni < 4; ++ni) {
        short4v pk;
#pragma unroll
        for (int e = 0; e < 4; ++e) pk[e] = (short)f2bf(acc[mi][ni][e]);
        const int hd = ni * 16 + r;
        const int c2 = q + 4 * (mi >> 1);
        *(short4v*)&vt_t[hd * 64 + ((c2 ^ (r & 7)) * 8) + (mi & 1) * 4] = pk;
      }
    return;
  }

#pragma unroll
  for (int mi = 0; mi < 4; ++mi) {
    const int row = m0 + wy * 64 + mi * 16 + q * 4;
#pragma unroll
    for (int ni = 0; ni < 4; ++ni) {
      const int col = n0 + wx * 64 + ni * 16 + r;
#pragma unroll
      for (int e = 0; e < 4; ++e)
        Cb[(size_t)(row + e) * 1024 + col] = f2bf(acc[mi][ni][e]);
    }
  }
}

__global__ __launch_bounds__(256) void gemm_qkv(const u16* __restrict__ A,
                                                const u16* __restrict__ Wq,
                                                const u16* __restrict__ Wk,
                                                const u16* __restrict__ Wv,
                                                u16* __restrict__ Cq,
                                                u16* __restrict__ Ck,
                                                u16* __restrict__ Vt) {
  __shared__ u16 Asm[128 * 64];
  __shared__ u16 Wsm[128 * 64];
  const int z = blockIdx.z;
  if (z == 2)
    gemm_body<2>(A, Wv, Vt, blockIdx.x, blockIdx.y, Asm, Wsm);
  else
    gemm_body<0>(A, z ? Wk : Wq, z ? Ck : Cq, blockIdx.x, blockIdx.y, Asm, Wsm);
}

// ---------------------------------------------------------------------------
// Output GEMM v2 (f32 out): tile 128x64, grid (64,16) = 1024 blocks.
// The old 128x128 grid was 512 blocks = 2 blocks/CU -- grid-starved, the
// same failure mode as R3 (GEMM @2/CU) and R9 (attn @1.4/CU): the 2-barrier
// staging drain is only hidden when co-resident blocks overlap it (m114).
// Cross-round arithmetic (R2/R5 non-attn residuals ~80-95 us beyond
// cast+gemm_qkv) points at gemm_out as the hidden cost. Now: 24 KB LDS
// (A 128x64 = 16 KB, W 64x64 = 8 KB) -> 4 blocks/CU from the grid, LDS cap
// 6. Waves 2Mx2N, per-wave 64x32 output (acc[4][2]); 6 gl_lds/thread/step
// (4 A + 2 W); same verified cl^(row&7) swizzle; 16 MFMA/K-step/wave.
// ---------------------------------------------------------------------------
__global__ __launch_bounds__(256) void gemm_out(const u16* __restrict__ A,
                                                const u16* __restrict__ W,
                                                float* __restrict__ C) {
  __shared__ u16 Asm[128 * 64];
  __shared__ u16 Wsm[64 * 64];
  const int t = threadIdx.x;
  const int w = t >> 6, l = t & 63;
  const int wy = w >> 1, wx = w & 1;
  const int q = l >> 4, r = l & 15;
  const int m0 = blockIdx.x * 128, n0 = blockIdx.y * 64;

  f32x4 acc[4][2] = {};

  for (int k0 = 0; k0 < 1024; k0 += 64) {
    __syncthreads();
#pragma unroll
    for (int i = 0; i < 4; ++i) {           // A: 1024 chunks
      const int c = t + i * 256;
      const int row = c >> 3, cl = c & 7;
      const int cg = cl ^ (row & 7);
      gl_lds16(A + (size_t)(m0 + row) * 1024 + k0 + cg * 8, &Asm[c * 8]);
    }
#pragma unroll
    for (int i = 0; i < 2; ++i) {           // W: 512 chunks
      const int c = t + i * 256;
      const int row = c >> 3, cl = c & 7;
      const int cg = cl ^ (row & 7);
      gl_lds16(W + (size_t)(n0 + row) * 1024 + k0 + cg * 8, &Wsm[c * 8]);
    }
    __syncthreads();
#pragma unroll
    for (int kf = 0; kf < 2; ++kf) {
      short8 af[4], bf[2];
#pragma unroll
      for (int mi = 0; mi < 4; ++mi) {
        const int rowA = wy * 64 + mi * 16 + r;
        af[mi] = *(const short8*)&Asm[rowA * 64 + ((kf * 4 + q) ^ (rowA & 7)) * 8];
      }
#pragma unroll
      for (int ni = 0; ni < 2; ++ni) {
        const int rowB = wx * 32 + ni * 16 + r;
        bf[ni] = *(const short8*)&Wsm[rowB * 64 + ((kf * 4 + q) ^ (rowB & 7)) * 8];
      }
#pragma unroll
      for (int mi = 0; mi < 4; ++mi)
#pragma unroll
        for (int ni = 0; ni < 2; ++ni)
          acc[mi][ni] = mfma32(af[mi], bf[ni], acc[mi][ni]);
    }
  }

#pragma unroll
  for (int mi = 0; mi < 4; ++mi) {
    const int row = m0 + wy * 64 + mi * 16 + q * 4;
#pragma unroll
    for (int ni = 0; ni < 2; ++ni) {
      const int col = n0 + wx * 32 + ni * 16 + r;
#pragma unroll
      for (int e = 0; e < 4; ++e)
        C[(size_t)(row + e) * 1024 + col] = acc[mi][ni][e];
    }
  }
}

// ---------------------------------------------------------------------------
// Flash attention v10 (unchanged; R6-verified): LPT order, XCD pinning,
// K dbuf + single V buffer (24 KB), counted vmcnt(4) before PV, register
// softmax via S^T trick, PV via mfma32, setprio on MFMA.
// ---------------------------------------------------------------------------
__global__ __launch_bounds__(128) void attn_v10(const u16* __restrict__ Qb,
                                                const u16* __restrict__ Kb,
                                                const u16* __restrict__ Vt,
                                                u16* __restrict__ Ob) {
  const int i = blockIdx.x;                      // 0..2047
  const int st = 31 - (i >> 6);                  // heavy q-tiles first (LPT)
  const int grp = (i & 7) + 8 * ((i >> 3) & 7);  // (b,h) group, XCD-pinned
  const int b = grp >> 4, h = grp & 15;
  const int t = threadIdx.x;
  const int w = t >> 6, l = t & 63;
  const int q = l >> 4, r = l & 15;

  __shared__ u16 Kd[2][4096];   // K double buffer (16 KB)
  __shared__ u16 Vd[4096];      // V single buffer (8 KB)

  const size_t kgbase = (size_t)(b * Sn) * Dn + h * 64;
  const size_t vgbase = (size_t)((b * Hn + h) * 32) * 4096;

  const u16* kg[4];
  const u16* vg[4];
#pragma unroll
  for (int ii = 0; ii < 4; ++ii) {
    const int c = t + ii * 128, row = c >> 3, cl = c & 7;
    kg[ii] = Kb + kgbase + (size_t)row * Dn + (cl ^ (row & 7)) * 8;
    vg[ii] = Vt + vgbase + c * 8;
  }
  const int rx = r & 7;
  const int b0 = r * 64 + ((q ^ rx) * 8);
  const int b1 = r * 64 + (((4 + q) ^ rx) * 8);

  const int qb64 = st * 64;

  short8 Qf[2][2];
#pragma unroll
  for (int mi = 0; mi < 2; ++mi)
#pragma unroll
    for (int kf = 0; kf < 2; ++kf)
      Qf[mi][kf] = *(const short8*)(Qb +
          (size_t)(b * Sn + qb64 + w * 32 + mi * 16 + r) * Dn + h * 64 +
          kf * 32 + q * 8);

  f32x4 O[2][4] = {};
  float l_[2] = {0.f, 0.f};

#pragma unroll
  for (int ii = 0; ii < 4; ++ii)
    gl_lds16(kg[ii], &Kd[0][(t + ii * 128) * 8]);

  const u16* kgt[4];
  const u16* vgt[4];
#pragma unroll
  for (int ii = 0; ii < 4; ++ii) {
    kgt[ii] = kg[ii] + 64 * Dn;
    vgt[ii] = vg[ii];
  }

  for (int jt = 0; jt <= st; ++jt) {
    __syncthreads();  // vmcnt(0)+barrier: K(jt) staged; V(jt-1) reads done

#pragma unroll
    for (int ii = 0; ii < 4; ++ii) {
      gl_lds16(vgt[ii], &Vd[(t + ii * 128) * 8]);
      vgt[ii] += 4096;
    }
    if (jt < st) {
      u16* kl = &Kd[(jt + 1) & 1][0];
#pragma unroll
      for (int ii = 0; ii < 4; ++ii) {
        gl_lds16(kgt[ii], kl + (t + ii * 128) * 8);
        kgt[ii] += 64 * Dn;
      }
    }

    const u16* KtA = &Kd[jt & 1][b0];
    const u16* KtB = &Kd[jt & 1][b1];

    short8 Kf[4][2];
#pragma unroll
    for (int ni = 0; ni < 4; ++ni) {
      Kf[ni][0] = *(const short8*)(KtA + ni * 1024);
      Kf[ni][1] = *(const short8*)(KtB + ni * 1024);
    }

    f32x4 S[2][4] = {};
    __builtin_amdgcn_s_setprio(1);
#pragma unroll
    for (int ni = 0; ni < 4; ++ni)
#pragma unroll
      for (int kf = 0; kf < 2; ++kf) {
        S[0][ni] = mfma32(Kf[ni][kf], Qf[0][kf], S[0][ni]);
        S[1][ni] = mfma32(Kf[ni][kf], Qf[1][kf], S[1][ni]);
      }
    __builtin_amdgcn_s_setprio(0);

    if (jt == st) {
#pragma unroll
      for (int mi = 0; mi < 2; ++mi) {
        const int qrow = w * 32 + mi * 16 + r;
#pragma unroll
        for (int ni = 0; ni < 4; ++ni) {
          const int key = ni * 16 + q * 4;
#pragma unroll
          for (int e = 0; e < 4; ++e)
            if (key + e > qrow) S[mi][ni][e] = -3.0e38f;
        }
      }
    }

    short8 P8[2][2];
#pragma unroll
    for (int mi = 0; mi < 2; ++mi)
#pragma unroll
      for (int np = 0; np < 2; ++np) {
        unsigned pw[4];
#pragma unroll
        for (int half = 0; half < 2; ++half) {
          const int ni = 2 * np + half;
          const float p0 = __builtin_amdgcn_exp2f(S[mi][ni][0]);
          const float p1 = __builtin_amdgcn_exp2f(S[mi][ni][1]);
          const float p2 = __builtin_amdgcn_exp2f(S[mi][ni][2]);
          const float p3 = __builtin_amdgcn_exp2f(S[mi][ni][3]);
          l_[mi] += (p0 + p1) + (p2 + p3);
          unsigned plo, phi;
          asm("v_cvt_pk_bf16_f32 %0, %1, %2" : "=v"(plo) : "v"(p0), "v"(p1));
          asm("v_cvt_pk_bf16_f32 %0, %1, %2" : "=v"(phi) : "v"(p2), "v"(p3));
          pw[half * 2] = plo;
          pw[half * 2 + 1] = phi;
        }
        const uint4v pk4 = {pw[0], pw[1], pw[2], pw[3]};
        P8[mi][np] = __builtin_bit_cast(short8, pk4);
      }

    if (jt < st)
      asm volatile("s_waitcnt vmcnt(4)" ::: "memory");
    else
      asm volatile("s_waitcnt vmcnt(0)" ::: "memory");
    __builtin_amdgcn_s_barrier();
    __builtin_amdgcn_sched_barrier(0);

    __builtin_amdgcn_s_setprio(1);
#pragma unroll
    for (int np = 0; np < 2; ++np) {
      const int vb = np ? b1 : b0;
#pragma unroll
      for (int ni2 = 0; ni2 < 4; ++ni2) {
        const short8 vvx = *(const short8*)(&Vd[vb + ni2 * 1024]);
        O[0][ni2] = mfma32(vvx, P8[0][np], O[0][ni2]);
        O[1][ni2] = mfma32(vvx, P8[1][np], O[1][ni2]);
      }
    }
    __builtin_amdgcn_s_setprio(0);
  }

#pragma unroll
  for (int mi = 0; mi < 2; ++mi) {
    float s = l_[mi];
    s += __shfl_xor(s, 16, 64);
    s += __shfl_xor(s, 32, 64);
    const float rl = __builtin_amdgcn_rcpf(s);
#pragma unroll
    for (int ni2 = 0; ni2 < 4; ++ni2) {
      short4v o;
#pragma unroll
      for (int e = 0; e < 4; ++e) o[e] = (short)f2bf(O[mi][ni2][e] * rl);
      *(short4v*)(Ob + (size_t)(b * Sn + qb64 + w * 32 + mi * 16 + r) * Dn +
                  h * 64 + ni2 * 16 + q * 4) = o;
    }
  }
}

// ---------------------------------------------------------------------------
extern "C" void kernel_launch(void* const* d_in, const int* in_sizes, int n_in,
                              void* d_out, int out_size, void* d_ws, size_t ws_size,
                              hipStream_t stream) {
  const float* x  = (const float*)d_in[0];
  const float* wq = (const float*)d_in[1];
  const float* wk = (const float*)d_in[2];
  const float* wv = (const float*)d_in[3];
  const float* wo = (const float*)d_in[4];
  float* out = (float*)d_out;

  u16* xb  = (u16*)d_ws;            // 8M u16
  u16* wqb = xb + 8388608;
  u16* wkb = wqb + 1048576;
  u16* wvb = wkb + 1048576;
  u16* wob = wvb + 1048576;
  u16* qb  = wob + 1048576;         // 8M each
  u16* kb  = qb + 8388608;
  u16* vt2 = kb + 8388608;          // V^T tiles, pre-swizzled
  u16* aob = vt2 + 8388608;

  cast_all<<<12288, 256, 0, stream>>>(
      (const float4*)x, (const float4*)wq, (const float4*)wk,
      (const float4*)wv, (const float4*)wo, (ushort4*)xb, (ushort4*)wqb,
      (ushort4*)wkb, (ushort4*)wvb, (ushort4*)wob);

  gemm_qkv<<<dim3(64, 8, 3), 256, 0, stream>>>(xb, wqb, wkb, wvb, qb, kb, vt2);

  attn_v10<<<2048, 128, 0, stream>>>(qb, kb, vt2, aob);

  gemm_out<<<dim3(64, 16), 256, 0, stream>>>(aob, wob, out);
}